// Round 2
// baseline (420.994 us; speedup 1.0000x reference)
//
#include <hip/hip_runtime.h>
#include <stdint.h>

#define B_ 8
#define HGRID 24
#define PN 576
#define PP1 577
#define HEADS 16
#define DD 1024
#define NL 9
#define KS 42
#define NREG 144
#define NCAND 432
#define DIST_THRESH_F 16.733200530681511f  /* sqrt(280) */

__device__ __forceinline__ float dist_penalty(int q, int p) {
    float dy = (float)(q / HGRID) - (float)(p / HGRID);
    float dx = (float)(q % HGRID) - (float)(p % HGRID);
    float d = sqrtf(dy * dy + dx * dx);
    return 1.0f - fminf(d / DIST_THRESH_F, 1.0f);
}

// A+B fused: metric[p] = sum over heads of attn[b,h,0,1+p]; then
// per-batch selection: top-3 per 2x2 region -> 432 candidates -> top-42 -> sort asc
__global__ __launch_bounds__(512) void select_kernel(const float* __restrict__ attn,
                                                     int* __restrict__ bench_out,
                                                     float* __restrict__ bench_f_out) {
    __shared__ float ms[PN];
    __shared__ int cand[NCAND];
    __shared__ unsigned long long key[512];
    __shared__ int bsort[KS];
    int b = blockIdx.x;
    int tid = threadIdx.x;
    const size_t plane = (size_t)PP1 * PP1;
    // metric: each thread handles p = tid and p = tid + 512 (if < 576)
    for (int p = tid; p < PN; p += 512) {
        size_t base = (size_t)b * HEADS * plane + 1 + p;
        float s = 0.f;
#pragma unroll
        for (int h = 0; h < HEADS; ++h) s += attn[base + (size_t)h * plane];
        ms[p] = s;
    }
    __syncthreads();
    if (tid < NREG) {
        int ry = tid / 12, rx = tid % 12;
        float v[4]; int pid[4];
#pragma unroll
        for (int e = 0; e < 4; ++e) {
            int gy = ry * 2 + (e >> 1), gx = rx * 2 + (e & 1);
            pid[e] = gy * HGRID + gx;
            v[e] = ms[pid[e]];
        }
        bool used[4] = {false, false, false, false};
#pragma unroll
        for (int n = 0; n < 3; ++n) {
            int best = -1; float bv = -1e30f;
#pragma unroll
            for (int e = 0; e < 4; ++e)
                if (!used[e] && v[e] > bv) { bv = v[e]; best = e; }
            used[best] = true;
            cand[tid * 3 + n] = pid[best];
        }
    }
    __syncthreads();
    if (tid < NCAND) {
        unsigned int sb = __float_as_uint(ms[cand[tid]]);
        key[tid] = ((unsigned long long)sb << 32) | (unsigned long long)(0xFFFFFFFFu - (unsigned)tid);
    } else {
        key[tid] = 0ull;
    }
    // bitonic sort, descending; ties -> smaller original index first (matches lax.top_k)
    for (int size = 2; size <= 512; size <<= 1) {
        for (int stride = size >> 1; stride > 0; stride >>= 1) {
            __syncthreads();
            int partner = tid ^ stride;
            if (partner > tid) {
                bool desc = ((tid & size) == 0);
                unsigned long long a = key[tid], c = key[partner];
                if (desc ? (a < c) : (a > c)) { key[tid] = c; key[partner] = a; }
            }
        }
    }
    __syncthreads();
    if (tid < KS) {
        int orig = (int)(0xFFFFFFFFu - (unsigned int)(key[tid] & 0xFFFFFFFFull));
        bsort[tid] = cand[orig];
    }
    __syncthreads();
    if (tid == 0) {  // tiny insertion sort ascending over 42 elements
        for (int i = 1; i < KS; ++i) {
            int x = bsort[i], j = i - 1;
            while (j >= 0 && bsort[j] > x) { bsort[j + 1] = bsort[j]; --j; }
            bsort[j + 1] = x;
        }
    }
    __syncthreads();
    if (tid < KS) {
        bench_out[b * KS + tid] = bsort[tid];
        bench_f_out[b * KS + tid] = (float)bsort[tid];
    }
}

// C: nrm[b][p][:] = normalize(mean over 9 layers of stacked_hs[l][b][p+1][:])
__global__ __launch_bounds__(256) void nrm_kernel(const float* __restrict__ shs,
                                                  float* __restrict__ nrm) {
    int blk = blockIdx.x;  // b*576 + p
    int b = blk / PN, p = blk % PN;
    int t = threadIdx.x;
    const size_t lstride = (size_t)B_ * PP1 * DD;
    size_t rowbase = ((size_t)b * PP1 + (p + 1)) * DD + t * 4;
    float4 acc = make_float4(0.f, 0.f, 0.f, 0.f);
#pragma unroll
    for (int l = 0; l < NL; ++l) {
        const float4 v = *reinterpret_cast<const float4*>(shs + rowbase + (size_t)l * lstride);
        acc.x += v.x; acc.y += v.y; acc.z += v.z; acc.w += v.w;
    }
    acc.x /= 9.0f; acc.y /= 9.0f; acc.z /= 9.0f; acc.w /= 9.0f;
    float ss = acc.x * acc.x + acc.y * acc.y + acc.z * acc.z + acc.w * acc.w;
#pragma unroll
    for (int o = 32; o > 0; o >>= 1) ss += __shfl_down(ss, o, 64);
    __shared__ float wsum[4];
    int lane = t & 63, wv = t >> 6;
    if (lane == 0) wsum[wv] = ss;
    __syncthreads();
    float total = wsum[0] + wsum[1] + wsum[2] + wsum[3];
    float scale = 1.0f / fmaxf(sqrtf(total), 1e-12f);
    float4 o4 = make_float4(acc.x * scale, acc.y * scale, acc.z * scale, acc.w * scale);
    *reinterpret_cast<float4*>(nrm + ((size_t)b * PN + p) * DD + t * 4) = o4;
}

// D: w_unnorm[b][k][p] = relu(dot(nrm[bench[k]], nrm[p])) * penalty(bench[k], p)
// tiled f32 GEMM: 42x32 tile per block, BK=64, 256 threads (16x16), 3x2 micro
__global__ __launch_bounds__(256) void sim_kernel(const float* __restrict__ nrm,
                                                  const int* __restrict__ bench,
                                                  float* __restrict__ w) {
    __shared__ __align__(16) float As[48][68];
    __shared__ __align__(16) float Bs[32][68];
    __shared__ int bsh[KS];
    int tile = blockIdx.x;  // 0..17
    int b = blockIdx.y;
    int tid = threadIdx.x;
    int tm = tid >> 4, tn = tid & 15;
    int p0 = tile * 32;
    if (tid < KS) bsh[tid] = bench[b * KS + tid];
    for (int i = tid; i < 6 * 68; i += 256) As[42 + i / 68][i % 68] = 0.f;
    float acc[3][2] = {};
    const float* nb = nrm + (size_t)b * PN * DD;
    for (int c = 0; c < 16; ++c) {
        int d0 = c * 64;
        __syncthreads();
        // stage A: 42 rows x 64 cols = 672 float4
#pragma unroll
        for (int it = 0; it < 3; ++it) {
            int idx = it * 256 + tid;
            if (idx < 672) {
                int row = idx >> 4, col = (idx & 15) * 4;
                float4 v = *reinterpret_cast<const float4*>(nb + (size_t)bsh[row] * DD + d0 + col);
                *reinterpret_cast<float4*>(&As[row][col]) = v;
            }
        }
        // stage B: 32 rows x 64 cols = 512 float4
#pragma unroll
        for (int it = 0; it < 2; ++it) {
            int idx = it * 256 + tid;
            int row = idx >> 4, col = (idx & 15) * 4;
            float4 v = *reinterpret_cast<const float4*>(nb + (size_t)(p0 + row) * DD + d0 + col);
            *reinterpret_cast<float4*>(&Bs[row][col]) = v;
        }
        __syncthreads();
#pragma unroll
        for (int kk = 0; kk < 64; kk += 4) {
            float4 a0 = *reinterpret_cast<const float4*>(&As[tm * 3 + 0][kk]);
            float4 a1 = *reinterpret_cast<const float4*>(&As[tm * 3 + 1][kk]);
            float4 a2 = *reinterpret_cast<const float4*>(&As[tm * 3 + 2][kk]);
            float4 b0 = *reinterpret_cast<const float4*>(&Bs[tn * 2 + 0][kk]);
            float4 b1 = *reinterpret_cast<const float4*>(&Bs[tn * 2 + 1][kk]);
            acc[0][0] += a0.x * b0.x + a0.y * b0.y + a0.z * b0.z + a0.w * b0.w;
            acc[0][1] += a0.x * b1.x + a0.y * b1.y + a0.z * b1.z + a0.w * b1.w;
            acc[1][0] += a1.x * b0.x + a1.y * b0.y + a1.z * b0.z + a1.w * b0.w;
            acc[1][1] += a1.x * b1.x + a1.y * b1.y + a1.z * b1.z + a1.w * b1.w;
            acc[2][0] += a2.x * b0.x + a2.y * b0.y + a2.z * b0.z + a2.w * b0.w;
            acc[2][1] += a2.x * b1.x + a2.y * b1.y + a2.z * b1.z + a2.w * b1.w;
        }
    }
#pragma unroll
    for (int i = 0; i < 3; ++i) {
        int k = tm * 3 + i;
        if (k >= KS) continue;
        int q = bsh[k];
#pragma unroll
        for (int j = 0; j < 2; ++j) {
            int p = p0 + tn * 2 + j;
            float s = fmaxf(acc[i][j], 0.f) * dist_penalty(q, p);
            w[((size_t)b * KS + k) * PN + p] = s;
        }
    }
}

// E: normalize each w row by (sum + 1e-8), then set w[b][k][bench[b][k]] = 1
__global__ __launch_bounds__(256) void wnorm_kernel(float* __restrict__ w,
                                                    const int* __restrict__ bench) {
    int blk = blockIdx.x;  // b*42 + k
    float* row = w + (size_t)blk * PN;
    int t = threadIdx.x;
    float v0 = row[t], v1 = row[t + 256], v2 = (t < 64) ? row[t + 512] : 0.f;
    float s = v0 + v1 + v2;
#pragma unroll
    for (int o = 32; o > 0; o >>= 1) s += __shfl_down(s, o, 64);
    __shared__ float ws4[4];
    int lane = t & 63, wv = t >> 6;
    if (lane == 0) ws4[wv] = s;
    __syncthreads();
    float total = ws4[0] + ws4[1] + ws4[2] + ws4[3];
    float scale = 1.0f / (total + 1e-8f);
    int bp = bench[blk];
    row[t] = (t == bp) ? 1.0f : v0 * scale;
    row[t + 256] = (t + 256 == bp) ? 1.0f : v1 * scale;
    if (t < 64) row[t + 512] = (t + 512 == bp) ? 1.0f : v2 * scale;
}

// F: out[b][k][:] = sum_p w[b][k][p] * hidden_agg[b][1+p][:]
// tiled f32 GEMM: 42x32 output tile, BK=32, 256 threads (16x16), 3x2 micro
__global__ __launch_bounds__(256) void out_kernel(const float* __restrict__ w,
                                                  const float* __restrict__ hidden,
                                                  float* __restrict__ out) {
    __shared__ __align__(16) float As[48][36];
    __shared__ __align__(16) float Bs[32][36];
    int ntile = blockIdx.x;  // 0..31
    int b = blockIdx.y;
    int tid = threadIdx.x;
    int tm = tid >> 4, tn = tid & 15;
    int n0 = ntile * 32;
    for (int i = tid; i < 6 * 36; i += 256) As[42 + i / 36][i % 36] = 0.f;
    float acc[3][2] = {};
    const float* wb = w + (size_t)b * KS * PN;
    const float* hb = hidden + ((size_t)b * PP1 + 1) * DD;
    for (int c = 0; c < 18; ++c) {
        int p0 = c * 32;
        __syncthreads();
        // stage A: 42 x 32 = 336 float4
#pragma unroll
        for (int it = 0; it < 2; ++it) {
            int idx = it * 256 + tid;
            if (idx < 336) {
                int row = idx >> 3, col = (idx & 7) * 4;
                float4 v = *reinterpret_cast<const float4*>(wb + (size_t)row * PN + p0 + col);
                *reinterpret_cast<float4*>(&As[row][col]) = v;
            }
        }
        // stage B: 32 x 32 = 256 float4
        {
            int row = tid >> 3, col = (tid & 7) * 4;
            float4 v = *reinterpret_cast<const float4*>(hb + (size_t)(p0 + row) * DD + n0 + col);
            *reinterpret_cast<float4*>(&Bs[row][col]) = v;
        }
        __syncthreads();
#pragma unroll
        for (int kk = 0; kk < 32; ++kk) {
            float a0 = As[tm * 3 + 0][kk], a1 = As[tm * 3 + 1][kk], a2 = As[tm * 3 + 2][kk];
            float b0 = Bs[kk][tn * 2 + 0], b1 = Bs[kk][tn * 2 + 1];
            acc[0][0] += a0 * b0; acc[0][1] += a0 * b1;
            acc[1][0] += a1 * b0; acc[1][1] += a1 * b1;
            acc[2][0] += a2 * b0; acc[2][1] += a2 * b1;
        }
    }
#pragma unroll
    for (int i = 0; i < 3; ++i) {
        int k = tm * 3 + i;
        if (k >= KS) continue;
#pragma unroll
        for (int j = 0; j < 2; ++j)
            out[((size_t)b * KS + k) * DD + n0 + tn * 2 + j] = acc[i][j];
    }
}

extern "C" void kernel_launch(void* const* d_in, const int* in_sizes, int n_in,
                              void* d_out, int out_size, void* d_ws, size_t ws_size,
                              hipStream_t stream) {
    const float* attn = (const float*)d_in[0];
    const float* hidden = (const float*)d_in[1];
    const float* shs = (const float*)d_in[2];
    float* out = (float*)d_out;
    float* bench_f = out + (size_t)B_ * KS * DD;  // bench written as floats after out

    char* ws = (char*)d_ws;
    float* nrm = (float*)ws;                           // 8*576*1024*4 = 18,874,368 B
    int* bench = (int*)(ws + 18874368);                // 8*42*4      = 1,344 B (pad 1,536)
    float* w = (float*)(ws + 18874368 + 1536);         // 8*42*576*4  = 774,144 B

    select_kernel<<<dim3(B_), dim3(512), 0, stream>>>(attn, bench, bench_f);
    nrm_kernel<<<dim3(B_ * PN), dim3(256), 0, stream>>>(shs, nrm);
    sim_kernel<<<dim3(18, B_), dim3(256), 0, stream>>>(nrm, bench, w);
    wnorm_kernel<<<dim3(B_ * KS), dim3(256), 0, stream>>>(w, bench);
    out_kernel<<<dim3(32, B_), dim3(256), 0, stream>>>(w, hidden, out);
}

// Round 4
// 378.050 us; speedup vs baseline: 1.1136x; 1.1136x over previous
//
#include <hip/hip_runtime.h>
#include <stdint.h>

#define B_ 8
#define HGRID 24
#define PN 576
#define PP1 577
#define HEADS 16
#define DD 1024
#define NL 9
#define KS 42
#define NREG 144
#define NCAND 432
#define KSPLIT 4
#define DIST_THRESH_F 16.733200530681511f  /* sqrt(280) */

__device__ __forceinline__ float dist_penalty(int q, int p) {
    float dy = (float)(q / HGRID) - (float)(p / HGRID);
    float dx = (float)(q % HGRID) - (float)(p % HGRID);
    float d = sqrtf(dy * dy + dx * dx);
    return 1.0f - fminf(d / DIST_THRESH_F, 1.0f);
}

// Fused metric + selection, rank-based (no bitonic, no serial insertion sort).
// metric[p] = sum_h attn[b,h,0,1+p]; top-3 per 2x2 region -> 432 cand;
// rank select top-42 (desc score, ties lower cand index); rank sort asc by patch id.
__global__ __launch_bounds__(512) void select_kernel(const float* __restrict__ attn,
                                                     int* __restrict__ bench_out,
                                                     float* __restrict__ bench_f_out) {
    __shared__ float ms[PN];
    __shared__ int cand[NCAND];
    __shared__ float csc[NCAND];
    __shared__ int sel[KS];
    int b = blockIdx.x;
    int tid = threadIdx.x;
    const size_t plane = (size_t)PP1 * PP1;
    for (int p = tid; p < PN; p += 512) {
        size_t base = (size_t)b * HEADS * plane + 1 + p;
        float s = 0.f;
#pragma unroll
        for (int h = 0; h < HEADS; ++h) s += attn[base + (size_t)h * plane];
        ms[p] = s;
    }
    __syncthreads();
    if (tid < NREG) {
        int ry = tid / 12, rx = tid % 12;
        float v[4]; int pid[4];
#pragma unroll
        for (int e = 0; e < 4; ++e) {
            int gy = ry * 2 + (e >> 1), gx = rx * 2 + (e & 1);
            pid[e] = gy * HGRID + gx;
            v[e] = ms[pid[e]];
        }
        bool used[4] = {false, false, false, false};
#pragma unroll
        for (int n = 0; n < 3; ++n) {
            int best = -1; float bv = -1e30f;
#pragma unroll
            for (int e = 0; e < 4; ++e)
                if (!used[e] && v[e] > bv) { bv = v[e]; best = e; }  // first max wins ties (lower idx)
            used[best] = true;
            cand[tid * 3 + n] = pid[best];
        }
    }
    __syncthreads();
    if (tid < NCAND) csc[tid] = ms[cand[tid]];
    __syncthreads();
    if (tid < NCAND) {
        float myv = csc[tid];
        int rank = 0;
#pragma unroll 8
        for (int j = 0; j < NCAND; ++j) {
            float vj = csc[j];  // broadcast read, conflict-free
            rank += (int)((vj > myv) || (vj == myv && j < tid));
        }
        if (rank < KS) sel[rank] = cand[tid];  // cand values distinct -> no collision
    }
    __syncthreads();
    if (tid < KS) {
        int v = sel[tid];
        int r2 = 0;
#pragma unroll
        for (int j = 0; j < KS; ++j) r2 += (int)(sel[j] < v);  // distinct -> permutation
        bench_out[b * KS + r2] = v;
        bench_f_out[b * KS + r2] = (float)v;
    }
}

// C: nrm[b][p][:] = normalize(mean over 9 layers of stacked_hs[l][b][p+1][:])
__global__ __launch_bounds__(256) void nrm_kernel(const float* __restrict__ shs,
                                                  float* __restrict__ nrm) {
    int blk = blockIdx.x;  // b*576 + p
    int b = blk / PN, p = blk % PN;
    int t = threadIdx.x;
    const size_t lstride = (size_t)B_ * PP1 * DD;
    size_t rowbase = ((size_t)b * PP1 + (p + 1)) * DD + t * 4;
    float4 acc = make_float4(0.f, 0.f, 0.f, 0.f);
#pragma unroll
    for (int l = 0; l < NL; ++l) {
        const float4 v = *reinterpret_cast<const float4*>(shs + rowbase + (size_t)l * lstride);
        acc.x += v.x; acc.y += v.y; acc.z += v.z; acc.w += v.w;
    }
    acc.x /= 9.0f; acc.y /= 9.0f; acc.z /= 9.0f; acc.w /= 9.0f;
    float ss = acc.x * acc.x + acc.y * acc.y + acc.z * acc.z + acc.w * acc.w;
#pragma unroll
    for (int o = 32; o > 0; o >>= 1) ss += __shfl_down(ss, o, 64);
    __shared__ float wsum[4];
    int lane = t & 63, wv = t >> 6;
    if (lane == 0) wsum[wv] = ss;
    __syncthreads();
    float total = wsum[0] + wsum[1] + wsum[2] + wsum[3];
    float scale = 1.0f / fmaxf(sqrtf(total), 1e-12f);
    float4 o4 = make_float4(acc.x * scale, acc.y * scale, acc.z * scale, acc.w * scale);
    *reinterpret_cast<float4*>(nrm + ((size_t)b * PN + p) * DD + t * 4) = o4;
}

// D: raw partial dot products, K-split by 4.
// wpart[kc][b][k][p] = sum over d in [kc*256, kc*256+256) of nrm[bench[k]][d]*nrm[p][d]
__global__ __launch_bounds__(256) void sim_kernel(const float* __restrict__ nrm,
                                                  const int* __restrict__ bench,
                                                  float* __restrict__ wpart) {
    __shared__ __align__(16) float As[48][68];
    __shared__ __align__(16) float Bs[32][68];
    __shared__ int bsh[KS];
    int tile = blockIdx.x;  // 0..17
    int b = blockIdx.y;
    int kc = blockIdx.z;    // 0..3
    int tid = threadIdx.x;
    int tm = tid >> 4, tn = tid & 15;
    int p0 = tile * 32;
    if (tid < KS) bsh[tid] = bench[b * KS + tid];
    for (int i = tid; i < 6 * 68; i += 256) As[42 + i / 68][i % 68] = 0.f;
    float acc[3][2] = {};
    const float* nb = nrm + (size_t)b * PN * DD;
    for (int c = kc * 4; c < kc * 4 + 4; ++c) {
        int d0 = c * 64;
        __syncthreads();
#pragma unroll
        for (int it = 0; it < 3; ++it) {  // A: 42 rows x 64 cols = 672 float4
            int idx = it * 256 + tid;
            if (idx < 672) {
                int row = idx >> 4, col = (idx & 15) * 4;
                float4 v = *reinterpret_cast<const float4*>(nb + (size_t)bsh[row] * DD + d0 + col);
                *reinterpret_cast<float4*>(&As[row][col]) = v;
            }
        }
#pragma unroll
        for (int it = 0; it < 2; ++it) {  // B: 32 rows x 64 cols = 512 float4
            int idx = it * 256 + tid;
            int row = idx >> 4, col = (idx & 15) * 4;
            float4 v = *reinterpret_cast<const float4*>(nb + (size_t)(p0 + row) * DD + d0 + col);
            *reinterpret_cast<float4*>(&Bs[row][col]) = v;
        }
        __syncthreads();
#pragma unroll
        for (int kk = 0; kk < 64; kk += 4) {
            float4 a0 = *reinterpret_cast<const float4*>(&As[tm * 3 + 0][kk]);
            float4 a1 = *reinterpret_cast<const float4*>(&As[tm * 3 + 1][kk]);
            float4 a2 = *reinterpret_cast<const float4*>(&As[tm * 3 + 2][kk]);
            float4 b0 = *reinterpret_cast<const float4*>(&Bs[tn * 2 + 0][kk]);
            float4 b1 = *reinterpret_cast<const float4*>(&Bs[tn * 2 + 1][kk]);
            acc[0][0] += a0.x * b0.x + a0.y * b0.y + a0.z * b0.z + a0.w * b0.w;
            acc[0][1] += a0.x * b1.x + a0.y * b1.y + a0.z * b1.z + a0.w * b1.w;
            acc[1][0] += a1.x * b0.x + a1.y * b0.y + a1.z * b0.z + a1.w * b0.w;
            acc[1][1] += a1.x * b1.x + a1.y * b1.y + a1.z * b1.z + a1.w * b1.w;
            acc[2][0] += a2.x * b0.x + a2.y * b0.y + a2.z * b0.z + a2.w * b0.w;
            acc[2][1] += a2.x * b1.x + a2.y * b1.y + a2.z * b1.z + a2.w * b1.w;
        }
    }
    float* wp = wpart + (size_t)kc * B_ * KS * PN;
#pragma unroll
    for (int i = 0; i < 3; ++i) {
        int k = tm * 3 + i;
        if (k >= KS) continue;
#pragma unroll
        for (int j = 0; j < 2; ++j) {
            int p = p0 + tn * 2 + j;
            wp[((size_t)b * KS + k) * PN + p] = acc[i][j];
        }
    }
}

// E: w[b][k][p] = relu(sum_kc wpart)*penalty; normalize row by (sum+1e-8); diag=1
__global__ __launch_bounds__(256) void wnorm_kernel(const float* __restrict__ wpart,
                                                    float* __restrict__ w,
                                                    const int* __restrict__ bench) {
    int blk = blockIdx.x;  // b*42 + k
    int q = bench[blk];
    const size_t kcs = (size_t)B_ * KS * PN;
    const float* row0 = wpart + (size_t)blk * PN;
    int t = threadIdx.x;
    float v[3];
    int pidx[3] = {t, t + 256, t + 512};
#pragma unroll
    for (int u = 0; u < 3; ++u) {
        int p = pidx[u];
        if (u < 2 || t < 64) {
            float s = row0[p] + row0[p + kcs] + row0[p + 2 * kcs] + row0[p + 3 * kcs];
            v[u] = fmaxf(s, 0.f) * dist_penalty(q, p);
        } else v[u] = 0.f;
    }
    float s = v[0] + v[1] + v[2];
#pragma unroll
    for (int o = 32; o > 0; o >>= 1) s += __shfl_down(s, o, 64);
    __shared__ float ws4[4];
    int lane = t & 63, wv = t >> 6;
    if (lane == 0) ws4[wv] = s;
    __syncthreads();
    float total = ws4[0] + ws4[1] + ws4[2] + ws4[3];
    float scale = 1.0f / (total + 1e-8f);
    float* orow = w + (size_t)blk * PN;
    orow[t] = (t == q) ? 1.0f : v[0] * scale;
    orow[t + 256] = (t + 256 == q) ? 1.0f : v[1] * scale;
    if (t < 64) orow[t + 512] = (t + 512 == q) ? 1.0f : v[2] * scale;
}

// F: out[b][k][:] = sum_p w[b][k][p] * hidden_agg[b][1+p][:]
__global__ __launch_bounds__(256) void out_kernel(const float* __restrict__ w,
                                                  const float* __restrict__ hidden,
                                                  float* __restrict__ out) {
    __shared__ __align__(16) float As[48][36];
    __shared__ __align__(16) float Bs[32][36];
    int ntile = blockIdx.x;  // 0..31
    int b = blockIdx.y;
    int tid = threadIdx.x;
    int tm = tid >> 4, tn = tid & 15;
    int n0 = ntile * 32;
    for (int i = tid; i < 6 * 36; i += 256) As[42 + i / 36][i % 36] = 0.f;
    float acc[3][2] = {};
    const float* wb = w + (size_t)b * KS * PN;
    const float* hb = hidden + ((size_t)b * PP1 + 1) * DD;
    for (int c = 0; c < 18; ++c) {
        int p0 = c * 32;
        __syncthreads();
#pragma unroll
        for (int it = 0; it < 2; ++it) {  // A: 42 x 32 = 336 float4
            int idx = it * 256 + tid;
            if (idx < 336) {
                int row = idx >> 3, col = (idx & 7) * 4;
                float4 v = *reinterpret_cast<const float4*>(wb + (size_t)row * PN + p0 + col);
                *reinterpret_cast<float4*>(&As[row][col]) = v;
            }
        }
        {  // B: 32 x 32 = 256 float4
            int row = tid >> 3, col = (tid & 7) * 4;
            float4 v = *reinterpret_cast<const float4*>(hb + (size_t)(p0 + row) * DD + n0 + col);
            *reinterpret_cast<float4*>(&Bs[row][col]) = v;
        }
        __syncthreads();
#pragma unroll
        for (int kk = 0; kk < 32; ++kk) {
            float a0 = As[tm * 3 + 0][kk], a1 = As[tm * 3 + 1][kk], a2 = As[tm * 3 + 2][kk];
            float b0 = Bs[kk][tn * 2 + 0], b1 = Bs[kk][tn * 2 + 1];
            acc[0][0] += a0 * b0; acc[0][1] += a0 * b1;
            acc[1][0] += a1 * b0; acc[1][1] += a1 * b1;
            acc[2][0] += a2 * b0; acc[2][1] += a2 * b1;
        }
    }
#pragma unroll
    for (int i = 0; i < 3; ++i) {
        int k = tm * 3 + i;
        if (k >= KS) continue;
#pragma unroll
        for (int j = 0; j < 2; ++j)
            out[((size_t)b * KS + k) * DD + n0 + tn * 2 + j] = acc[i][j];
    }
}

extern "C" void kernel_launch(void* const* d_in, const int* in_sizes, int n_in,
                              void* d_out, int out_size, void* d_ws, size_t ws_size,
                              hipStream_t stream) {
    const float* attn = (const float*)d_in[0];
    const float* hidden = (const float*)d_in[1];
    const float* shs = (const float*)d_in[2];
    float* out = (float*)d_out;
    float* bench_f = out + (size_t)B_ * KS * DD;  // bench as floats after out

    char* ws = (char*)d_ws;
    float* nrm = (float*)ws;                                   // 18,874,368 B
    int* bench = (int*)(ws + 18874368);                        // 1,536 B (padded)
    float* wpart = (float*)(ws + 18874368 + 1536);             // 4*8*42*576*4 = 3,096,576 B
    float* w = (float*)(ws + 18874368 + 1536 + 3096576);       // 774,144 B

    select_kernel<<<dim3(B_), dim3(512), 0, stream>>>(attn, bench, bench_f);
    nrm_kernel<<<dim3(B_ * PN), dim3(256), 0, stream>>>(shs, nrm);
    sim_kernel<<<dim3(18, B_, KSPLIT), dim3(256), 0, stream>>>(nrm, bench, wpart);
    wnorm_kernel<<<dim3(B_ * KS), dim3(256), 0, stream>>>(wpart, w, bench);
    out_kernel<<<dim3(32, B_), dim3(256), 0, stream>>>(w, hidden, out);
}